// Round 2
// baseline (559.686 us; speedup 1.0000x reference)
//
#include <hip/hip_runtime.h>
#include <math.h>

// B=64, L=1024, C=128, K=6, P=6, Dp=8, D=4, Dd=12, ITERS=2
#define EPSQ 1e-9f

constexpr int NPOS = 8;    // positions per block
constexpr int XROW = 132;  // padded LDS row stride for X^T (128 + 4)
constexpr int SROW = 52;   // padded LDS row stride for primaries / u_hat (48 + 4)

__device__ __forceinline__ float g16sum(float x) {
    x += __shfl_xor(x, 1);
    x += __shfl_xor(x, 2);
    x += __shfl_xor(x, 4);
    x += __shfl_xor(x, 8);
    return x;
}

__device__ __forceinline__ float dot4(float4 a, float4 b) {
    float r = a.x * b.x;
    r = fmaf(a.y, b.y, r);
    r = fmaf(a.z, b.z, r);
    r = fmaf(a.w, b.w, r);
    return r;
}

// Dynamic routing (ITERS=2) + output write; lane = d*16 + q, q<12 active.
__device__ __forceinline__ void route_and_write(const float* uh, int d, int q, bool act,
                                                float* __restrict__ out, long pos)
{
    // iter 1: c = softmax(0) = 0.25
    float s = 0.f;
    #pragma unroll
    for (int k = 0; k < 6; ++k) s += uh[k];
    s *= 0.25f;
    float s2 = g16sum(s * s);
    float v = s * (s2 / (1.0f + s2) / (sqrtf(s2) + EPSQ));

    // iter 2
    float ss = 0.f;
    #pragma unroll
    for (int k = 0; k < 6; ++k) {
        float b = g16sum(uh[k] * v);
        float m = fmaxf(b, __shfl_xor(b, 16));
        m = fmaxf(m, __shfl_xor(m, 32));
        float e = expf(b - m);
        float es = e + __shfl_xor(e, 16);
        es += __shfl_xor(es, 32);
        ss = fmaf(e / es, uh[k], ss);
    }
    float ss2 = g16sum(ss * ss);
    float vv = ss * (ss2 / (1.0f + ss2) / (sqrtf(ss2) + EPSQ));
    if (act) out[pos * 48 + d * 12 + q] = vv;
}

__global__ __launch_bounds__(256, 4) void capsule_kernel(
    const float* __restrict__ X,    // [65536][128][6]
    const float* __restrict__ Wp,   // [48][128]
    const float* __restrict__ bp,   // [48]
    const float* __restrict__ W,    // [6][48 dq][48 p]
    float* __restrict__ out)        // [65536][48]
{
    __shared__ __align__(16) float smem[48 * XROW + 48 * SROW]; // 6336 + 2496 floats = 35.3 KB
    float* sXT = smem;              // [48 rows=(pos*6+k)][XROW cols=c]
    float* sS  = smem + 48 * XROW;  // [48 rows=(pos*6+k)][SROW cols=p] primaries
    float* sU  = smem;              // reuse of sXT region: [48][SROW cols=dq] u_hat

    const int t = threadIdx.x;
    const long pos_base = (long)blockIdx.x * NPOS;

    // ---- stage + transpose X: global [pos][c][k] (coalesced float4) -> sXT[pos*6+k][c]
    {
        const float4* __restrict__ src = (const float4*)(X + pos_base * 768);
        #pragma unroll
        for (int it = 0; it < 6; ++it) {
            float4 v = src[t + 256 * it];
            int e = 4 * (t + 256 * it);
            #pragma unroll
            for (int j = 0; j < 4; ++j) {
                int ee = e + j;
                int pos = ee / 768;
                int rem = ee - pos * 768;
                int c = rem / 6;
                int k = rem - 6 * c;
                sXT[(pos * 6 + k) * XROW + c] = ((const float*)&v)[j];
            }
        }
    }
    __syncthreads();

    // ---- projection GEMM: out[row=(pos,k)][p] = sum_c sXT[row][c] * Wp[p][c]  (+bias)
    // thread tile 3x3: rows {3*ri..+2} (per-lane LDS reads), cols {3*cj..+2} (Wp, L1)
    const int ri = t & 15;   // varies across lanes -> LDS per-lane rows (2-way, free)
    const int cj = t >> 4;   // 4 values per wave -> Wp loads near-broadcast
    {
        float acc[3][3];
        #pragma unroll
        for (int s = 0; s < 3; ++s) {
            float b = bp[3 * cj + s];
            acc[0][s] = b; acc[1][s] = b; acc[2][s] = b;
        }
        const float4* __restrict__ B0 = (const float4*)(Wp + (3 * cj) * 128);
        const float* a0p = sXT + (3 * ri + 0) * XROW;
        const float* a1p = sXT + (3 * ri + 1) * XROW;
        const float* a2p = sXT + (3 * ri + 2) * XROW;
        #pragma unroll 4
        for (int cq = 0; cq < 32; ++cq) {
            float4 a0 = *(const float4*)(a0p + 4 * cq);
            float4 a1 = *(const float4*)(a1p + 4 * cq);
            float4 a2 = *(const float4*)(a2p + 4 * cq);
            float4 b0 = B0[cq];
            float4 b1 = B0[cq + 32];
            float4 b2 = B0[cq + 64];
            acc[0][0] += dot4(a0, b0); acc[0][1] += dot4(a0, b1); acc[0][2] += dot4(a0, b2);
            acc[1][0] += dot4(a1, b0); acc[1][1] += dot4(a1, b1); acc[1][2] += dot4(a1, b2);
            acc[2][0] += dot4(a2, b0); acc[2][1] += dot4(a2, b1); acc[2][2] += dot4(a2, b2);
        }
        #pragma unroll
        for (int r = 0; r < 3; ++r)
            #pragma unroll
            for (int s = 0; s < 3; ++s)
                sS[(3 * ri + r) * SROW + 3 * cj + s] = acc[r][s];
    }
    __syncthreads();

    // ---- squash primaries over Dp=8 groups: 48 rows x 6 groups = 288 groups
    for (int g = t; g < 288; g += 256) {
        int row = g / 6;
        int colg = (g - 6 * row) * 8;
        float* p = sS + row * SROW + colg;
        float4 v0 = *(float4*)p;
        float4 v1 = *(float4*)(p + 4);
        float s2 = v0.x * v0.x + v0.y * v0.y + v0.z * v0.z + v0.w * v0.w
                 + v1.x * v1.x + v1.y * v1.y + v1.z * v1.z + v1.w * v1.w;
        float r = s2 / (1.0f + s2) / (sqrtf(s2) + EPSQ);
        v0.x *= r; v0.y *= r; v0.z *= r; v0.w *= r;
        v1.x *= r; v1.y *= r; v1.z *= r; v1.w *= r;
        *(float4*)p = v0;
        *(float4*)(p + 4) = v1;
    }
    __syncthreads();

    // ---- u_hat GEMM: sU[row=(pos,k)][dq] = sum_p sS[row][p] * W[k][dq][p]
    // same 3x3 thread tile; W read from global (L2-hot, 8 distinct addrs/instr)
    {
        float acc[3][3];
        #pragma unroll
        for (int r = 0; r < 3; ++r)
            #pragma unroll
            for (int s = 0; s < 3; ++s) acc[r][s] = 0.f;
        const int row0 = 3 * ri;
        const float* __restrict__ Wb0 = W + (long)((row0    ) % 6) * 2304;
        const float* __restrict__ Wb1 = W + (long)((row0 + 1) % 6) * 2304;
        const float* __restrict__ Wb2 = W + (long)((row0 + 2) % 6) * 2304;
        const float* a0p = sS + (row0 + 0) * SROW;
        const float* a1p = sS + (row0 + 1) * SROW;
        const float* a2p = sS + (row0 + 2) * SROW;
        #pragma unroll 3
        for (int p4 = 0; p4 < 12; ++p4) {
            float4 a0 = *(const float4*)(a0p + 4 * p4);
            float4 a1 = *(const float4*)(a1p + 4 * p4);
            float4 a2 = *(const float4*)(a2p + 4 * p4);
            #pragma unroll
            for (int s = 0; s < 3; ++s) {
                int dq = 3 * cj + s;
                float4 w0 = *(const float4*)(Wb0 + dq * 48 + 4 * p4);
                float4 w1 = *(const float4*)(Wb1 + dq * 48 + 4 * p4);
                float4 w2 = *(const float4*)(Wb2 + dq * 48 + 4 * p4);
                acc[0][s] += dot4(a0, w0);
                acc[1][s] += dot4(a1, w1);
                acc[2][s] += dot4(a2, w2);
            }
        }
        #pragma unroll
        for (int r = 0; r < 3; ++r)
            #pragma unroll
            for (int s = 0; s < 3; ++s)
                sU[(row0 + r) * SROW + 3 * cj + s] = acc[r][s];
    }
    __syncthreads();

    // ---- routing: wave handles positions (wave, wave+4); lane = d*16+q
    const int wave = t >> 6;
    const int lane = t & 63;
    const int d = lane >> 4;
    const int q = lane & 15;
    const bool act = (q < 12);
    const int dq = d * 12 + (act ? q : 11);

    float uh0[6], uh1[6];
    #pragma unroll
    for (int k = 0; k < 6; ++k) {
        float v0 = sU[(wave * 6 + k) * SROW + dq];
        float v1 = sU[((wave + 4) * 6 + k) * SROW + dq];
        uh0[k] = act ? v0 : 0.f;
        uh1[k] = act ? v1 : 0.f;
    }
    route_and_write(uh0, d, q, act, out, pos_base + wave);
    route_and_write(uh1, d, q, act, out, pos_base + wave + 4);
}

extern "C" void kernel_launch(void* const* d_in, const int* in_sizes, int n_in,
                              void* d_out, int out_size, void* d_ws, size_t ws_size,
                              hipStream_t stream) {
    const float* X  = (const float*)d_in[0];   // [64,1024,128,6]
    const float* Wp = (const float*)d_in[1];   // [48,128]
    const float* bp = (const float*)d_in[2];   // [48]
    const float* W  = (const float*)d_in[3];   // [6,4,12,48]
    float* out = (float*)d_out;                // [65536,48]

    const int n_pos = 64 * 1024;
    dim3 grid(n_pos / NPOS), block(256);
    hipLaunchKernelGGL(capsule_kernel, grid, block, 0, stream, X, Wp, bp, W, out);
}

// Round 3
// 555.599 us; speedup vs baseline: 1.0074x; 1.0074x over previous
//
#include <hip/hip_runtime.h>
#include <math.h>

// B=64, L=1024, C=128, K=6, P=6, Dp=8, D=4, Dd=12, ITERS=2
#define EPSQ 1e-9f

constexpr int NPOS = 8;    // positions per block
constexpr int XROW = 132;  // padded LDS row stride for X^T (16B-aligned rows, 2-way reads = free)
constexpr int SROW = 52;   // padded LDS row stride for primaries / u_hat

__device__ __forceinline__ float g16sum(float x) {
    x += __shfl_xor(x, 1);
    x += __shfl_xor(x, 2);
    x += __shfl_xor(x, 4);
    x += __shfl_xor(x, 8);
    return x;
}

__device__ __forceinline__ float dot4(float4 a, float4 b) {
    float r = a.x * b.x;
    r = fmaf(a.y, b.y, r);
    r = fmaf(a.z, b.z, r);
    r = fmaf(a.w, b.w, r);
    return r;
}

// Dynamic routing (ITERS=2) + output write; lane = d*16 + q, q<12 active.
__device__ __forceinline__ void route_and_write(const float* uh, int d, int q, bool act,
                                                float* __restrict__ out, long pos)
{
    // iter 1: c = softmax(0) = 0.25
    float s = 0.f;
    #pragma unroll
    for (int k = 0; k < 6; ++k) s += uh[k];
    s *= 0.25f;
    float s2 = g16sum(s * s);
    float v = s * (s2 / (1.0f + s2) / (sqrtf(s2) + EPSQ));

    // iter 2
    float ss = 0.f;
    #pragma unroll
    for (int k = 0; k < 6; ++k) {
        float b = g16sum(uh[k] * v);
        float m = fmaxf(b, __shfl_xor(b, 16));
        m = fmaxf(m, __shfl_xor(m, 32));
        float e = expf(b - m);
        float es = e + __shfl_xor(e, 16);
        es += __shfl_xor(es, 32);
        ss = fmaf(e / es, uh[k], ss);
    }
    float ss2 = g16sum(ss * ss);
    float vv = ss * (ss2 / (1.0f + ss2) / (sqrtf(ss2) + EPSQ));
    if (act) out[pos * 48 + d * 12 + q] = vv;
}

__global__ __launch_bounds__(256) __attribute__((amdgpu_waves_per_eu(4, 4)))
void capsule_kernel(
    const float* __restrict__ X,    // [65536][128][6]
    const float* __restrict__ Wp,   // [48][128]
    const float* __restrict__ bp,   // [48]
    const float* __restrict__ W,    // [6][48 dq][48 p]
    float* __restrict__ out)        // [65536][48]
{
    __shared__ __align__(16) float smem[48 * XROW + 48 * SROW]; // 34.9 KB -> 4 blocks/CU
    float* sXT = smem;              // [48 rows=(pos*6+k)][XROW cols=c]
    float* sS  = smem + 48 * XROW;  // [48 rows=(pos*6+k)][SROW cols=p] primaries
    float* sU  = smem;              // reuse of sXT region: [48][SROW cols=dq] u_hat

    const int t = threadIdx.x;
    const long pos_base = (long)blockIdx.x * NPOS;

    // ---- stage + transpose X (div-free): thread t -> pos=t>>5, tp=t&31.
    // Reads 6 consecutive float4 = elements m=0..23 at rem = 24*tp + m:
    //   c = 4*tp + m/6, k = m%6  (m/6, m%6 are compile-time constants)
    // Repacks into 6 contiguous float4 LDS writes (one per k).
    {
        const int tp = t & 31;
        const int pos = t >> 5;
        const float4* __restrict__ src =
            (const float4*)(X + pos_base * 768) + pos * 192 + tp * 6;
        float4 v0 = src[0], v1 = src[1], v2 = src[2], v3 = src[3], v4 = src[4], v5 = src[5];
        float* base = sXT + (pos * 6) * XROW + 4 * tp;
        *(float4*)(base + 0 * XROW) = make_float4(v0.x, v1.z, v3.x, v4.z); // k=0: m=0,6,12,18
        *(float4*)(base + 1 * XROW) = make_float4(v0.y, v1.w, v3.y, v4.w); // k=1: m=1,7,13,19
        *(float4*)(base + 2 * XROW) = make_float4(v0.z, v2.x, v3.z, v5.x); // k=2: m=2,8,14,20
        *(float4*)(base + 3 * XROW) = make_float4(v0.w, v2.y, v3.w, v5.y); // k=3: m=3,9,15,21
        *(float4*)(base + 4 * XROW) = make_float4(v1.x, v2.z, v4.x, v5.z); // k=4: m=4,10,16,22
        *(float4*)(base + 5 * XROW) = make_float4(v1.y, v2.w, v4.y, v5.w); // k=5: m=5,11,17,23
    }
    __syncthreads();

    // ---- projection GEMM: sS[row=(pos,k)][p] = bias[p] + sum_c sXT[row][c]*Wp[p][c]
    // 16x16 thread grid, 3x3 register tile.
    const int ri = t & 15;
    const int cj = t >> 4;
    {
        float acc[3][3];
        #pragma unroll
        for (int s = 0; s < 3; ++s) {
            float b = bp[3 * cj + s];
            acc[0][s] = b; acc[1][s] = b; acc[2][s] = b;
        }
        const float4* __restrict__ B0 = (const float4*)(Wp + (3 * cj) * 128);
        const float* a0p = sXT + (3 * ri + 0) * XROW;
        const float* a1p = sXT + (3 * ri + 1) * XROW;
        const float* a2p = sXT + (3 * ri + 2) * XROW;
        #pragma unroll 4
        for (int cq = 0; cq < 32; ++cq) {
            float4 a0 = *(const float4*)(a0p + 4 * cq);
            float4 a1 = *(const float4*)(a1p + 4 * cq);
            float4 a2 = *(const float4*)(a2p + 4 * cq);
            float4 b0 = B0[cq];
            float4 b1 = B0[cq + 32];
            float4 b2 = B0[cq + 64];
            acc[0][0] += dot4(a0, b0); acc[0][1] += dot4(a0, b1); acc[0][2] += dot4(a0, b2);
            acc[1][0] += dot4(a1, b0); acc[1][1] += dot4(a1, b1); acc[1][2] += dot4(a1, b2);
            acc[2][0] += dot4(a2, b0); acc[2][1] += dot4(a2, b1); acc[2][2] += dot4(a2, b2);
        }
        #pragma unroll
        for (int r = 0; r < 3; ++r)
            #pragma unroll
            for (int s = 0; s < 3; ++s)
                sS[(3 * ri + r) * SROW + 3 * cj + s] = acc[r][s];
    }
    __syncthreads();

    // ---- squash primaries over Dp=8 groups: 48 rows x 6 groups
    for (int g = t; g < 288; g += 256) {
        int row = g / 6;
        int colg = (g - 6 * row) * 8;
        float* p = sS + row * SROW + colg;
        float4 v0 = *(float4*)p;
        float4 v1 = *(float4*)(p + 4);
        float s2 = v0.x * v0.x + v0.y * v0.y + v0.z * v0.z + v0.w * v0.w
                 + v1.x * v1.x + v1.y * v1.y + v1.z * v1.z + v1.w * v1.w;
        float r = s2 / (1.0f + s2) / (sqrtf(s2) + EPSQ);
        v0.x *= r; v0.y *= r; v0.z *= r; v0.w *= r;
        v1.x *= r; v1.y *= r; v1.z *= r; v1.w *= r;
        *(float4*)p = v0;
        *(float4*)(p + 4) = v1;
    }
    __syncthreads();

    // ---- u_hat GEMM: sU[row=(pos,k)][dq] = sum_p sS[row][p] * W[k][dq][p]
    // W from global: 8 distinct L1 lines per load instr (2 k-slices x 4 dq), L1/L2-hot.
    {
        float acc[3][3];
        #pragma unroll
        for (int r = 0; r < 3; ++r)
            #pragma unroll
            for (int s = 0; s < 3; ++s) acc[r][s] = 0.f;
        const int row0 = 3 * ri;
        const float* __restrict__ Wb0 = W + (long)((row0    ) % 6) * 2304;
        const float* __restrict__ Wb1 = W + (long)((row0 + 1) % 6) * 2304;
        const float* __restrict__ Wb2 = W + (long)((row0 + 2) % 6) * 2304;
        const float* a0p = sS + (row0 + 0) * SROW;
        const float* a1p = sS + (row0 + 1) * SROW;
        const float* a2p = sS + (row0 + 2) * SROW;
        #pragma unroll 3
        for (int p4 = 0; p4 < 12; ++p4) {
            float4 a0 = *(const float4*)(a0p + 4 * p4);
            float4 a1 = *(const float4*)(a1p + 4 * p4);
            float4 a2 = *(const float4*)(a2p + 4 * p4);
            #pragma unroll
            for (int s = 0; s < 3; ++s) {
                int dq = 3 * cj + s;
                float4 w0 = *(const float4*)(Wb0 + dq * 48 + 4 * p4);
                float4 w1 = *(const float4*)(Wb1 + dq * 48 + 4 * p4);
                float4 w2 = *(const float4*)(Wb2 + dq * 48 + 4 * p4);
                acc[0][s] += dot4(a0, w0);
                acc[1][s] += dot4(a1, w1);
                acc[2][s] += dot4(a2, w2);
            }
        }
        #pragma unroll
        for (int r = 0; r < 3; ++r)
            #pragma unroll
            for (int s = 0; s < 3; ++s)
                sU[(row0 + r) * SROW + 3 * cj + s] = acc[r][s];
    }
    __syncthreads();

    // ---- routing: wave handles positions (wave, wave+4); lane = d*16+q
    const int wave = t >> 6;
    const int lane = t & 63;
    const int d = lane >> 4;
    const int q = lane & 15;
    const bool act = (q < 12);
    const int dq = d * 12 + (act ? q : 11);

    float uh0[6], uh1[6];
    #pragma unroll
    for (int k = 0; k < 6; ++k) {
        float v0 = sU[(wave * 6 + k) * SROW + dq];
        float v1 = sU[((wave + 4) * 6 + k) * SROW + dq];
        uh0[k] = act ? v0 : 0.f;
        uh1[k] = act ? v1 : 0.f;
    }
    route_and_write(uh0, d, q, act, out, pos_base + wave);
    route_and_write(uh1, d, q, act, out, pos_base + wave + 4);
}

extern "C" void kernel_launch(void* const* d_in, const int* in_sizes, int n_in,
                              void* d_out, int out_size, void* d_ws, size_t ws_size,
                              hipStream_t stream) {
    const float* X  = (const float*)d_in[0];   // [64,1024,128,6]
    const float* Wp = (const float*)d_in[1];   // [48,128]
    const float* bp = (const float*)d_in[2];   // [48]
    const float* W  = (const float*)d_in[3];   // [6,4,12,48]
    float* out = (float*)d_out;                // [65536,48]

    const int n_pos = 64 * 1024;
    dim3 grid(n_pos / NPOS), block(256);
    hipLaunchKernelGGL(capsule_kernel, grid, block, 0, stream, X, Wp, bp, W, out);
}

// Round 4
// 534.574 us; speedup vs baseline: 1.0470x; 1.0393x over previous
//
#include <hip/hip_runtime.h>
#include <math.h>

// B=64, L=1024, C=128, K=6, P=6, Dp=8, D=4, Dd=12, ITERS=2
#define EPSQ 1e-9f

constexpr int NPOS = 8;    // positions per block
constexpr int XROW = 132;  // padded LDS row stride for X^T
constexpr int SROW = 52;   // padded LDS row stride for primaries / u_hat

__device__ __forceinline__ float g16sum(float x) {
    x += __shfl_xor(x, 1);
    x += __shfl_xor(x, 2);
    x += __shfl_xor(x, 4);
    x += __shfl_xor(x, 8);
    return x;
}

__device__ __forceinline__ float dot4(float4 a, float4 b) {
    float r = a.x * b.x;
    r = fmaf(a.y, b.y, r);
    r = fmaf(a.z, b.z, r);
    r = fmaf(a.w, b.w, r);
    return r;
}

// Dynamic routing (ITERS=2) on 6 scalar u_hat values — NO arrays, all registers.
__device__ __forceinline__ void route_and_write(float u0, float u1, float u2,
                                                float u3, float u4, float u5,
                                                int d, int q, bool act,
                                                float* __restrict__ out, long pos)
{
    // iter 1: c = softmax(0) = 0.25
    float s = (u0 + u1 + u2 + u3 + u4 + u5) * 0.25f;
    float s2 = g16sum(s * s);
    float v = s * (s2 / (1.0f + s2) / (sqrtf(s2) + EPSQ));

    // iter 2: b[k,d] = <u_k, v>; c = softmax_d(b); s = sum_k c_k u_k
    float ss = 0.f;
#define ROUTE_K(UK)                                        \
    {                                                      \
        float b = g16sum((UK) * v);                        \
        float m = fmaxf(b, __shfl_xor(b, 16));             \
        m = fmaxf(m, __shfl_xor(m, 32));                   \
        float e = expf(b - m);                             \
        float es = e + __shfl_xor(e, 16);                  \
        es += __shfl_xor(es, 32);                          \
        ss = fmaf(e / es, (UK), ss);                       \
    }
    ROUTE_K(u0) ROUTE_K(u1) ROUTE_K(u2) ROUTE_K(u3) ROUTE_K(u4) ROUTE_K(u5)
#undef ROUTE_K
    float ss2 = g16sum(ss * ss);
    float vv = ss * (ss2 / (1.0f + ss2) / (sqrtf(ss2) + EPSQ));
    if (act) out[pos * 48 + d * 12 + q] = vv;
}

__global__ __launch_bounds__(256)
void capsule_kernel(
    const float* __restrict__ X,    // [65536][128][6]
    const float* __restrict__ Wp,   // [48][128]
    const float* __restrict__ bp,   // [48]
    const float* __restrict__ W,    // [6][48 dq][48 p]
    float* __restrict__ out)        // [65536][48]
{
    __shared__ __align__(16) float smem[48 * XROW + 48 * SROW]; // 34.9 KB -> 4 blocks/CU
    float* sXT = smem;              // [48 rows=(pos*6+k)][XROW cols=c]
    float* sS  = smem + 48 * XROW;  // [48 rows=(pos*6+k)][SROW cols=p] primaries
    float* sU  = smem;              // reuse of sXT region: [48][SROW cols=dq] u_hat

    const int t = threadIdx.x;
    const long pos_base = (long)blockIdx.x * NPOS;

    // ---- stage + transpose X (div-free, 6x float4 in, 6x float4 LDS out)
    {
        const int tp = t & 31;
        const int pos = t >> 5;
        const float4* __restrict__ src =
            (const float4*)(X + pos_base * 768) + pos * 192 + tp * 6;
        float4 v0 = src[0], v1 = src[1], v2 = src[2], v3 = src[3], v4 = src[4], v5 = src[5];
        float* base = sXT + (pos * 6) * XROW + 4 * tp;
        *(float4*)(base + 0 * XROW) = make_float4(v0.x, v1.z, v3.x, v4.z); // k=0
        *(float4*)(base + 1 * XROW) = make_float4(v0.y, v1.w, v3.y, v4.w); // k=1
        *(float4*)(base + 2 * XROW) = make_float4(v0.z, v2.x, v3.z, v5.x); // k=2
        *(float4*)(base + 3 * XROW) = make_float4(v0.w, v2.y, v3.w, v5.y); // k=3
        *(float4*)(base + 4 * XROW) = make_float4(v1.x, v2.z, v4.x, v5.z); // k=4
        *(float4*)(base + 5 * XROW) = make_float4(v1.y, v2.w, v4.y, v5.w); // k=5
    }
    __syncthreads();

    const int ri = t & 15;
    const int cj = t >> 4;

    // ---- projection GEMM: sS[row][p] = bias + sum_c sXT[row][c]*Wp[p][c]
    // 3x3 register tile, all named scalars (no arrays -> no scratch).
    {
        const float b0i = bp[3 * cj + 0];
        const float b1i = bp[3 * cj + 1];
        const float b2i = bp[3 * cj + 2];
        float acc00 = b0i, acc01 = b1i, acc02 = b2i;
        float acc10 = b0i, acc11 = b1i, acc12 = b2i;
        float acc20 = b0i, acc21 = b1i, acc22 = b2i;

        const float4* __restrict__ B0 = (const float4*)(Wp + (3 * cj) * 128);
        const float* a0p = sXT + (3 * ri + 0) * XROW;
        const float* a1p = sXT + (3 * ri + 1) * XROW;
        const float* a2p = sXT + (3 * ri + 2) * XROW;
        #pragma unroll 4
        for (int cq = 0; cq < 32; ++cq) {
            float4 a0 = *(const float4*)(a0p + 4 * cq);
            float4 a1 = *(const float4*)(a1p + 4 * cq);
            float4 a2 = *(const float4*)(a2p + 4 * cq);
            float4 b0 = B0[cq];
            float4 b1 = B0[cq + 32];
            float4 b2 = B0[cq + 64];
            acc00 += dot4(a0, b0); acc01 += dot4(a0, b1); acc02 += dot4(a0, b2);
            acc10 += dot4(a1, b0); acc11 += dot4(a1, b1); acc12 += dot4(a1, b2);
            acc20 += dot4(a2, b0); acc21 += dot4(a2, b1); acc22 += dot4(a2, b2);
        }
        float* s0 = sS + (3 * ri + 0) * SROW + 3 * cj;
        float* s1 = sS + (3 * ri + 1) * SROW + 3 * cj;
        float* s2 = sS + (3 * ri + 2) * SROW + 3 * cj;
        s0[0] = acc00; s0[1] = acc01; s0[2] = acc02;
        s1[0] = acc10; s1[1] = acc11; s1[2] = acc12;
        s2[0] = acc20; s2[1] = acc21; s2[2] = acc22;
    }
    __syncthreads();

    // ---- squash primaries over Dp=8 groups: 48 rows x 6 groups
    for (int g = t; g < 288; g += 256) {
        int row = g / 6;
        int colg = (g - 6 * row) * 8;
        float* p = sS + row * SROW + colg;
        float4 v0 = *(float4*)p;
        float4 v1 = *(float4*)(p + 4);
        float s2 = v0.x * v0.x + v0.y * v0.y + v0.z * v0.z + v0.w * v0.w
                 + v1.x * v1.x + v1.y * v1.y + v1.z * v1.z + v1.w * v1.w;
        float r = s2 / (1.0f + s2) / (sqrtf(s2) + EPSQ);
        v0.x *= r; v0.y *= r; v0.z *= r; v0.w *= r;
        v1.x *= r; v1.y *= r; v1.z *= r; v1.w *= r;
        *(float4*)p = v0;
        *(float4*)(p + 4) = v1;
    }
    __syncthreads();

    // ---- u_hat GEMM: sU[row][dq] = sum_p sS[row][p] * W[k(row)][dq][p]
    {
        float u00 = 0.f, u01 = 0.f, u02 = 0.f;
        float u10 = 0.f, u11 = 0.f, u12 = 0.f;
        float u20 = 0.f, u21 = 0.f, u22 = 0.f;
        const int row0 = 3 * ri;
        const float* __restrict__ Wb0 = W + (long)((row0    ) % 6) * 2304 + (3 * cj) * 48;
        const float* __restrict__ Wb1 = W + (long)((row0 + 1) % 6) * 2304 + (3 * cj) * 48;
        const float* __restrict__ Wb2 = W + (long)((row0 + 2) % 6) * 2304 + (3 * cj) * 48;
        const float* a0p = sS + (row0 + 0) * SROW;
        const float* a1p = sS + (row0 + 1) * SROW;
        const float* a2p = sS + (row0 + 2) * SROW;
        #pragma unroll 3
        for (int p4 = 0; p4 < 12; ++p4) {
            float4 a0 = *(const float4*)(a0p + 4 * p4);
            float4 a1 = *(const float4*)(a1p + 4 * p4);
            float4 a2 = *(const float4*)(a2p + 4 * p4);
            float4 w00 = *(const float4*)(Wb0 + 0 * 48 + 4 * p4);
            float4 w01 = *(const float4*)(Wb0 + 1 * 48 + 4 * p4);
            float4 w02 = *(const float4*)(Wb0 + 2 * 48 + 4 * p4);
            float4 w10 = *(const float4*)(Wb1 + 0 * 48 + 4 * p4);
            float4 w11 = *(const float4*)(Wb1 + 1 * 48 + 4 * p4);
            float4 w12 = *(const float4*)(Wb1 + 2 * 48 + 4 * p4);
            float4 w20 = *(const float4*)(Wb2 + 0 * 48 + 4 * p4);
            float4 w21 = *(const float4*)(Wb2 + 1 * 48 + 4 * p4);
            float4 w22 = *(const float4*)(Wb2 + 2 * 48 + 4 * p4);
            u00 += dot4(a0, w00); u01 += dot4(a0, w01); u02 += dot4(a0, w02);
            u10 += dot4(a1, w10); u11 += dot4(a1, w11); u12 += dot4(a1, w12);
            u20 += dot4(a2, w20); u21 += dot4(a2, w21); u22 += dot4(a2, w22);
        }
        float* s0 = sU + (row0 + 0) * SROW + 3 * cj;
        float* s1 = sU + (row0 + 1) * SROW + 3 * cj;
        float* s2 = sU + (row0 + 2) * SROW + 3 * cj;
        s0[0] = u00; s0[1] = u01; s0[2] = u02;
        s1[0] = u10; s1[1] = u11; s1[2] = u12;
        s2[0] = u20; s2[1] = u21; s2[2] = u22;
    }
    __syncthreads();

    // ---- routing: wave handles positions (wave, wave+4); lane = d*16+q
    const int wave = t >> 6;
    const int lane = t & 63;
    const int d = lane >> 4;
    const int q = lane & 15;
    const bool act = (q < 12);
    const int dq = d * 12 + (act ? q : 11);

    {
        const float* u = sU + (wave * 6) * SROW + dq;
        float a0 = u[0 * SROW], a1 = u[1 * SROW], a2 = u[2 * SROW];
        float a3 = u[3 * SROW], a4 = u[4 * SROW], a5 = u[5 * SROW];
        if (!act) { a0 = a1 = a2 = a3 = a4 = a5 = 0.f; }
        route_and_write(a0, a1, a2, a3, a4, a5, d, q, act, out, pos_base + wave);
    }
    {
        const float* u = sU + ((wave + 4) * 6) * SROW + dq;
        float a0 = u[0 * SROW], a1 = u[1 * SROW], a2 = u[2 * SROW];
        float a3 = u[3 * SROW], a4 = u[4 * SROW], a5 = u[5 * SROW];
        if (!act) { a0 = a1 = a2 = a3 = a4 = a5 = 0.f; }
        route_and_write(a0, a1, a2, a3, a4, a5, d, q, act, out, pos_base + wave + 4);
    }
}

extern "C" void kernel_launch(void* const* d_in, const int* in_sizes, int n_in,
                              void* d_out, int out_size, void* d_ws, size_t ws_size,
                              hipStream_t stream) {
    const float* X  = (const float*)d_in[0];   // [64,1024,128,6]
    const float* Wp = (const float*)d_in[1];   // [48,128]
    const float* bp = (const float*)d_in[2];   // [48]
    const float* W  = (const float*)d_in[3];   // [6,4,12,48]
    float* out = (float*)d_out;                // [65536,48]

    const int n_pos = 64 * 1024;
    dim3 grid(n_pos / NPOS), block(256);
    hipLaunchKernelGGL(capsule_kernel, grid, block, 0, stream, X, Wp, bp, W, out);
}

// Round 5
// 338.578 us; speedup vs baseline: 1.6530x; 1.5789x over previous
//
#include <hip/hip_runtime.h>
#include <hip/hip_bf16.h>
#include <math.h>

// B=64, L=1024, C=128, K=6, P=6, Dp=8, D=4, Dd=12, ITERS=2
#define EPSQ 1e-9f

typedef float  floatx4 __attribute__((ext_vector_type(4)));
typedef short  short8  __attribute__((ext_vector_type(8)));
typedef unsigned short u16;
typedef unsigned int   u32;

constexpr int TP  = 16;  // positions per block
constexpr int SA  = 40;  // ushort stride, stage-1 A rows (32 data + 8 pad) = 80 B, 16B-aligned
constexpr int SS  = 52;  // dword stride, sS/sU rows (48 data + 4 pad) = 208 B, 16B-aligned
constexpr int SA2 = 40;  // ushort stride, stage-2 A rows (32 data + 8 pad)

// fp32 -> (hi, lo) bf16 pair-packed as u32 (2 elements per call)
__device__ __forceinline__ void cvt_hilo(float a, float b, u32& hi, u32& lo) {
    __hip_bfloat162 h = __float22bfloat162_rn(make_float2(a, b));
    float2 hf = __bfloat1622float2(h);
    __hip_bfloat162 l = __float22bfloat162_rn(make_float2(a - hf.x, b - hf.y));
    __builtin_memcpy(&hi, &h, 4);
    __builtin_memcpy(&lo, &l, 4);
}

__device__ __forceinline__ float g16sum(float x) {
    x += __shfl_xor(x, 1);
    x += __shfl_xor(x, 2);
    x += __shfl_xor(x, 4);
    x += __shfl_xor(x, 8);
    return x;
}

// Dynamic routing (ITERS=2), named scalars only (R4 lesson: no local arrays).
__device__ __forceinline__ void route_and_write(float u0, float u1, float u2,
                                                float u3, float u4, float u5,
                                                int d, int q, bool act,
                                                float* __restrict__ out, long pos)
{
    float s = (u0 + u1 + u2 + u3 + u4 + u5) * 0.25f;
    float s2 = g16sum(s * s);
    float v = s * (s2 / (1.0f + s2) / (sqrtf(s2) + EPSQ));

    float ss = 0.f;
#define ROUTE_K(UK)                                        \
    {                                                      \
        float b = g16sum((UK) * v);                        \
        float mm = fmaxf(b, __shfl_xor(b, 16));            \
        mm = fmaxf(mm, __shfl_xor(mm, 32));                \
        float e = __expf(b - mm);                          \
        float es = e + __shfl_xor(e, 16);                  \
        es += __shfl_xor(es, 32);                          \
        ss = fmaf(e / es, (UK), ss);                       \
    }
    ROUTE_K(u0) ROUTE_K(u1) ROUTE_K(u2) ROUTE_K(u3) ROUTE_K(u4) ROUTE_K(u5)
#undef ROUTE_K
    float ss2 = g16sum(ss * ss);
    float vv = ss * (ss2 / (1.0f + ss2) / (sqrtf(ss2) + EPSQ));
    if (act) out[pos * 48 + d * 12 + q] = vv;
}

// ---- prep: convert Wp/W into MFMA-B-fragment-ready bf16 hi/lo layouts in ws.
// wpf: [var2][ct3][kc4][lane64][j8]  = Wp[p=ct*16+(lane&15)][c=kc*32+quad*8+j]
// wf : [var2][k6][ct3][kc2][lane64][j8] = W[k][dq=ct*16+(lane&15)][p=kc*32+quad*8+j], 0 if p>=48
__global__ void prep_kernel(const float* __restrict__ Wp, const float* __restrict__ W,
                            u16* __restrict__ wpf, u16* __restrict__ wf) {
    int gid = blockIdx.x * 256 + threadIdx.x;
    int stride = gridDim.x * 256;
    for (int i = gid; i < 12288; i += stride) {
        int j = i & 7, lane = (i >> 3) & 63, kc = (i >> 9) & 3, vt = i >> 11;
        int var = (vt >= 3) ? 1 : 0;
        int ct = vt - 3 * var;
        int p = ct * 16 + (lane & 15);
        int c = kc * 32 + (lane >> 4) * 8 + j;
        float x = Wp[p * 128 + c];
        __hip_bfloat16 hb = __float2bfloat16(x);
        if (var) { float hf = __bfloat162float(hb); hb = __float2bfloat16(x - hf); }
        u16 u; __builtin_memcpy(&u, &hb, 2);
        wpf[i] = u;
    }
    for (int i = gid; i < 36864; i += stride) {
        int j = i & 7, lane = (i >> 3) & 63, kc = (i >> 9) & 1, q3 = i >> 10;
        int ct = q3 % 3, kk = q3 / 3;       // kk = var*6 + k
        int k = kk % 6, var = kk / 6;
        int dq = ct * 16 + (lane & 15);
        int p = kc * 32 + (lane >> 4) * 8 + j;
        float x = (p < 48) ? W[(k * 48 + dq) * 48 + p] : 0.f;
        __hip_bfloat16 hb = __float2bfloat16(x);
        if (var) { float hf = __bfloat162float(hb); hb = __float2bfloat16(x - hf); }
        u16 u; __builtin_memcpy(&u, &hb, 2);
        wf[i] = u;
    }
}

__global__ __launch_bounds__(256)
void capsule_kernel(
    const float* __restrict__ X,    // [65536][128][6]
    const float* __restrict__ bp,   // [48]
    const u16* __restrict__ wpf,    // prepped Wp fragments
    const u16* __restrict__ wf,     // prepped W fragments
    float* __restrict__ out)        // [65536][48]
{
    // LDS: region0 (19,968 B): sA (stage1, 15,360) -> sS -> sU ; region1: sA2 (15,360)
    __shared__ __align__(16) char raw[19968 + 2 * 96 * SA2 * 2];
    float* sS   = (float*)raw;                  // [96][SS] f32
    float* sU   = (float*)raw;                  // [96][SS] f32 (after sS dead)
    u16*  sAh   = (u16*)raw;                    // [96][SA]
    u16*  sAl   = sAh + 96 * SA;
    u16*  sA2h  = (u16*)(raw + 19968);          // [96][SA2], rows = k*16 + pos
    u16*  sA2l  = sA2h + 96 * SA2;

    const int t    = threadIdx.x;
    const int lane = t & 63;
    const int w    = t >> 6;
    const int m    = lane & 15;
    const int quad = lane >> 4;
    const long pos_base = (long)blockIdx.x * TP;

    // ================= stage 1: projection  sS[(pos*6+k)][p] = X·Wp^T + bp =================
    floatx4 acc_a = {0.f,0.f,0.f,0.f}, acc_b = {0.f,0.f,0.f,0.f}, acc_c = {0.f,0.f,0.f,0.f},
            acc_d = {0.f,0.f,0.f,0.f}, acc_e = {0.f,0.f,0.f,0.f};

#define S1_TILE(ACC, TI)                                                              \
    { int T = w + 4 * (TI);                                                           \
      if (T < 18) {                                                                   \
        int rt = T / 3, ct = T - 3 * rt;                                              \
        short8 ah = *(const short8*)(sAh + (rt * 16 + m) * SA + quad * 8);            \
        short8 al = *(const short8*)(sAl + (rt * 16 + m) * SA + quad * 8);            \
        short8 bh = *(const short8*)(wpf + ((ct * 4 + kc) * 64 + lane) * 8);          \
        short8 bl = *(const short8*)(wpf + (((3 + ct) * 4 + kc) * 64 + lane) * 8);    \
        ACC = __builtin_amdgcn_mfma_f32_16x16x32_bf16(ah, bh, ACC, 0, 0, 0);          \
        ACC = __builtin_amdgcn_mfma_f32_16x16x32_bf16(ah, bl, ACC, 0, 0, 0);          \
        ACC = __builtin_amdgcn_mfma_f32_16x16x32_bf16(al, bh, ACC, 0, 0, 0);          \
      } }

    #pragma unroll
    for (int kc = 0; kc < 4; ++kc) {
        if (kc > 0) __syncthreads();
        // stage chunk c in [kc*32, kc*32+32): thread -> (pos = t>>4, c-pair = t&15)
        {
            int pos = t >> 4, cp = t & 15;
            const float4* src = (const float4*)(X + (pos_base + pos) * 768 + kc * 192) + cp * 3;
            float4 f0 = src[0], f1 = src[1], f2 = src[2];
            u16* bh = sAh + (pos * 6) * SA + cp * 2;
            u16* bl = sAl + (pos * 6) * SA + cp * 2;
            u32 h, l;
            cvt_hilo(f0.x, f1.z, h, l); *(u32*)(bh + 0 * SA) = h; *(u32*)(bl + 0 * SA) = l;
            cvt_hilo(f0.y, f1.w, h, l); *(u32*)(bh + 1 * SA) = h; *(u32*)(bl + 1 * SA) = l;
            cvt_hilo(f0.z, f2.x, h, l); *(u32*)(bh + 2 * SA) = h; *(u32*)(bl + 2 * SA) = l;
            cvt_hilo(f0.w, f2.y, h, l); *(u32*)(bh + 3 * SA) = h; *(u32*)(bl + 3 * SA) = l;
            cvt_hilo(f1.x, f2.z, h, l); *(u32*)(bh + 4 * SA) = h; *(u32*)(bl + 4 * SA) = l;
            cvt_hilo(f1.y, f2.w, h, l); *(u32*)(bh + 5 * SA) = h; *(u32*)(bl + 5 * SA) = l;
        }
        __syncthreads();
        S1_TILE(acc_a, 0) S1_TILE(acc_b, 1) S1_TILE(acc_c, 2) S1_TILE(acc_d, 3) S1_TILE(acc_e, 4)
    }
#undef S1_TILE
    __syncthreads();   // all MFMA reads of sA done before sS overlays it

#define S1_EPI(ACC, TI)                                                   \
    { int T = w + 4 * (TI);                                               \
      if (T < 18) {                                                       \
        int rt = T / 3, ct = T - 3 * rt;                                  \
        float b = bp[ct * 16 + m];                                        \
        float* dst = sS + (rt * 16 + quad * 4) * SS + ct * 16 + m;        \
        dst[0 * SS] = ACC.x + b; dst[1 * SS] = ACC.y + b;                 \
        dst[2 * SS] = ACC.z + b; dst[3 * SS] = ACC.w + b;                 \
      } }
    S1_EPI(acc_a, 0) S1_EPI(acc_b, 1) S1_EPI(acc_c, 2) S1_EPI(acc_d, 3) S1_EPI(acc_e, 4)
#undef S1_EPI
    __syncthreads();

    // ---- squash primaries: 96 rows x 6 groups of 8
    for (int g = t; g < 576; g += 256) {
        int row = g / 6, grp = g - 6 * row;
        float* p = sS + row * SS + grp * 8;
        float4 v0 = *(float4*)p;
        float4 v1 = *(float4*)(p + 4);
        float s2 = v0.x * v0.x + v0.y * v0.y + v0.z * v0.z + v0.w * v0.w
                 + v1.x * v1.x + v1.y * v1.y + v1.z * v1.z + v1.w * v1.w;
        float r = s2 / (1.0f + s2) / (sqrtf(s2) + EPSQ);
        v0.x *= r; v0.y *= r; v0.z *= r; v0.w *= r;
        v1.x *= r; v1.y *= r; v1.z *= r; v1.w *= r;
        *(float4*)p = v0;
        *(float4*)(p + 4) = v1;
    }
    __syncthreads();

    // ================= stage 2: u_hat  sU[(pos*6+k)][dq] = sum_p sS[(pos,k)][p]·W[k][dq][p] =====
    floatx4 uacc_a = {0.f,0.f,0.f,0.f}, uacc_b = {0.f,0.f,0.f,0.f}, uacc_c = {0.f,0.f,0.f,0.f},
            uacc_d = {0.f,0.f,0.f,0.f}, uacc_e = {0.f,0.f,0.f,0.f};

#define S2_TILE(ACC, TI)                                                                    \
    { int T = w + 4 * (TI);                                                                 \
      if (T < 18) {                                                                         \
        int k = T / 3, ct = T - 3 * k;                                                      \
        short8 ah = *(const short8*)(sA2h + (k * 16 + m) * SA2 + quad * 8);                 \
        short8 al = *(const short8*)(sA2l + (k * 16 + m) * SA2 + quad * 8);                 \
        short8 bh = *(const short8*)(wf + (((k * 3 + ct) * 2 + kc2) * 64 + lane) * 8);      \
        short8 bl = *(const short8*)(wf + ((((6 + k) * 3 + ct) * 2 + kc2) * 64 + lane) * 8);\
        ACC = __builtin_amdgcn_mfma_f32_16x16x32_bf16(ah, bh, ACC, 0, 0, 0);                \
        ACC = __builtin_amdgcn_mfma_f32_16x16x32_bf16(ah, bl, ACC, 0, 0, 0);                \
        ACC = __builtin_amdgcn_mfma_f32_16x16x32_bf16(al, bh, ACC, 0, 0, 0);                \
      } }

    #pragma unroll
    for (int kc2 = 0; kc2 < 2; ++kc2) {
        if (kc2 > 0) __syncthreads();
        // convert sS -> sA2 (rows re-ordered to k*16+pos) for p-chunk kc2
        if (t < 192) {
            int rowA2 = t >> 1, half = t & 1;
            int pos = rowA2 & 15, k = rowA2 >> 4;
            int rowS = pos * 6 + k;
            u16* dh = sA2h + rowA2 * SA2 + half * 16;
            u16* dl = sA2l + rowA2 * SA2 + half * 16;
            if (kc2 == 0 || half == 0) {
                const float4* s = (const float4*)(sS + rowS * SS + kc2 * 32 + half * 16);
                #pragma unroll
                for (int g = 0; g < 4; ++g) {
                    float4 v = s[g];
                    u32 h0, l0, h1, l1;
                    cvt_hilo(v.x, v.y, h0, l0);
                    cvt_hilo(v.z, v.w, h1, l1);
                    *(u32*)(dh + g * 4)     = h0; *(u32*)(dh + g * 4 + 2) = h1;
                    *(u32*)(dl + g * 4)     = l0; *(u32*)(dl + g * 4 + 2) = l1;
                }
            } else {
                // kc2==1, half==1: p = 48..63 -> zero pad
                #pragma unroll
                for (int g = 0; g < 4; ++g) {
                    *(u32*)(dh + g * 4) = 0u; *(u32*)(dh + g * 4 + 2) = 0u;
                    *(u32*)(dl + g * 4) = 0u; *(u32*)(dl + g * 4 + 2) = 0u;
                }
            }
        }
        __syncthreads();
        S2_TILE(uacc_a, 0) S2_TILE(uacc_b, 1) S2_TILE(uacc_c, 2) S2_TILE(uacc_d, 3) S2_TILE(uacc_e, 4)
    }
#undef S2_TILE

    // epilogue: C frag -> sU (overlays sS; no one reads sS anymore)
#define S2_EPI(ACC, TI)                                                   \
    { int T = w + 4 * (TI);                                               \
      if (T < 18) {                                                       \
        int k = T / 3, ct = T - 3 * k;                                    \
        sU[((quad * 4 + 0) * 6 + k) * SS + ct * 16 + m] = ACC.x;          \
        sU[((quad * 4 + 1) * 6 + k) * SS + ct * 16 + m] = ACC.y;          \
        sU[((quad * 4 + 2) * 6 + k) * SS + ct * 16 + m] = ACC.z;          \
        sU[((quad * 4 + 3) * 6 + k) * SS + ct * 16 + m] = ACC.w;          \
      } }
    S2_EPI(uacc_a, 0) S2_EPI(uacc_b, 1) S2_EPI(uacc_c, 2) S2_EPI(uacc_d, 3) S2_EPI(uacc_e, 4)
#undef S2_EPI
    __syncthreads();

    // ================= routing: wave handles 4 positions =================
    const int d = lane >> 4;
    const int q = lane & 15;
    const bool act = (q < 12);
    const int dqi = d * 12 + (act ? q : 0);

    #pragma unroll
    for (int i = 0; i < 4; ++i) {
        int pos = w * 4 + i;
        const float* u = sU + (pos * 6) * SS + dqi;
        float a0 = u[0 * SS], a1 = u[1 * SS], a2 = u[2 * SS];
        float a3 = u[3 * SS], a4 = u[4 * SS], a5 = u[5 * SS];
        if (!act) { a0 = a1 = a2 = a3 = a4 = a5 = 0.f; }
        route_and_write(a0, a1, a2, a3, a4, a5, d, q, act, out, pos_base + pos);
    }
}

extern "C" void kernel_launch(void* const* d_in, const int* in_sizes, int n_in,
                              void* d_out, int out_size, void* d_ws, size_t ws_size,
                              hipStream_t stream) {
    const float* X  = (const float*)d_in[0];   // [64,1024,128,6]
    const float* Wp = (const float*)d_in[1];   // [48,128]
    const float* bp = (const float*)d_in[2];   // [48]
    const float* W  = (const float*)d_in[3];   // [6,4,12,48]
    float* out = (float*)d_out;                // [65536,48]

    u16* wpf = (u16*)d_ws;            // 12288 u16 = 24,576 B
    u16* wf  = wpf + 12288;           // 36864 u16 = 73,728 B  (total 98,304 B of ws)

    hipLaunchKernelGGL(prep_kernel, dim3(48), dim3(256), 0, stream, Wp, W, wpf, wf);

    const int n_pos = 64 * 1024;
    hipLaunchKernelGGL(capsule_kernel, dim3(n_pos / TP), dim3(256), 0, stream,
                       X, bp, wpf, wf, out);
}